// Round 4
// baseline (347.559 us; speedup 1.0000x reference)
//
#include <hip/hip_runtime.h>

typedef __attribute__((ext_vector_type(8))) short short8;
typedef __attribute__((ext_vector_type(4))) float float4v;
typedef __attribute__((ext_vector_type(4))) unsigned short ushort4v;

#define NB 32
#define NC 512
#define NL 512
#define NH 8
#define NDK 64

__device__ __forceinline__ unsigned short f2b(float f) {
  union { float f; unsigned int u; } v; v.f = f;
  unsigned int r = v.u + 0x7FFFu + ((v.u >> 16) & 1u);
  return (unsigned short)(r >> 16);
}

__device__ __forceinline__ void gld16(const void* g, void* l) {
  __builtin_amdgcn_global_load_lds(
      (const __attribute__((address_space(1))) unsigned int*)g,
      (__attribute__((address_space(3))) unsigned int*)l, 16, 0, 0);
}

__device__ __forceinline__ float4v bmfma(short8 a, short8 b, float4v c) {
  return __builtin_amdgcn_mfma_f32_16x16x32_bf16(a, b, c, 0, 0, 0);
}

// ---- fp32 -> bf16 weight conversion, 4 matrices in one launch --------------
__global__ __launch_bounds__(256) void cvt4_kernel(
    const float* __restrict__ a, const float* __restrict__ b,
    const float* __restrict__ c, const float* __restrict__ d,
    unsigned short* __restrict__ oa, unsigned short* __restrict__ ob,
    unsigned short* __restrict__ oc, unsigned short* __restrict__ od) {
  int m = blockIdx.y;
  const float* src = (m == 0) ? a : (m == 1) ? b : (m == 2) ? c : d;
  unsigned short* dst = (m == 0) ? oa : (m == 1) ? ob : (m == 2) ? oc : od;
  int i = (blockIdx.x * 256 + threadIdx.x) * 4;
  float4v v = *(const float4v*)(src + i);
  ushort4v o;
  o.x = f2b(v.x); o.y = f2b(v.y); o.z = f2b(v.z); o.w = f2b(v.w);
  *(ushort4v*)(dst + i) = o;
}

// ---- posconv: conv(pos, dw_w) + dw_b, batch-independent; out (L,C) fp32 ----
__global__ __launch_bounds__(256) void posconv_kernel(
    const float* __restrict__ pos,
    const float* __restrict__ qw, const float* __restrict__ qb,
    const float* __restrict__ kw, const float* __restrict__ kb,
    float* __restrict__ pq, float* __restrict__ pk) {
  int t = blockIdx.y, l = blockIdx.x;
  const float* w  = t ? kw : qw;
  const float* bb = t ? kb : qb;
  float* outp = t ? pk : pq;
  for (int c = threadIdx.x; c < NC; c += 256) {
    float acc = bb[c];
#pragma unroll
    for (int tt = 0; tt < 7; ++tt) {
      int ll = l + tt - 3;
      if (ll >= 0 && ll < NL) acc += pos[(size_t)ll * NC + c] * w[c * 7 + tt];
    }
    outp[(size_t)l * NC + c] = acc;
  }
}

// ---- depthwise conv(7); posconv(+bias) added for q,k; writes yT (B,L,C) ----
__global__ __launch_bounds__(256) void dw_kernel(
    const float* __restrict__ q, const float* __restrict__ k, const float* __restrict__ v,
    const float* __restrict__ pq, const float* __restrict__ pk,
    const float* __restrict__ qw, const float* __restrict__ kw, const float* __restrict__ vw,
    const float* __restrict__ vb,
    unsigned short* __restrict__ yq, unsigned short* __restrict__ yk,
    unsigned short* __restrict__ yv) {
  int z = blockIdx.z;
  int t = z >> 5, b = z & 31;
  const float* x   = (t == 0) ? q  : (t == 1) ? k  : v;
  const float* dww = (t == 0) ? qw : (t == 1) ? kw : vw;
  const float* pcv = (t == 0) ? pq : pk;  // only used when t<2
  unsigned short* yT = (t == 0) ? yq : (t == 1) ? yk : yv;
  int c0 = blockIdx.y * 64, l0 = blockIdx.x * 64;
  int tid = threadIdx.x;
  __shared__ __attribute__((aligned(16))) float xs[64 * 100];
#pragma unroll
  for (int it = 0; it < 6; ++it) {
    int idx = tid + 256 * it;  // 0..1535
    int row = idx / 24, f4 = idx - row * 24;
    int l = l0 - 16 + f4 * 4;
    const float* px = x + ((size_t)b * NC + c0 + row) * NL + l;
    float v0 = 0.f, v1 = 0.f, v2 = 0.f, v3 = 0.f;
    if (l >= 0 && l + 3 < NL) {
      float4v vv = *(const float4v*)px;
      v0 = vv.x; v1 = vv.y; v2 = vv.z; v3 = vv.w;
    } else {
      if (l + 0 >= 0 && l + 0 < NL) v0 = px[0];
      if (l + 1 >= 0 && l + 1 < NL) v1 = px[1];
      if (l + 2 >= 0 && l + 2 < NL) v2 = px[2];
      if (l + 3 >= 0 && l + 3 < NL) v3 = px[3];
    }
    float* xr = xs + row * 100 + f4 * 4;
    xr[0] = v0; xr[1] = v1; xr[2] = v2; xr[3] = v3;
  }
  __syncthreads();
  int cl = tid & 63;
  int llb = (tid >> 6) * 16;
  int c = c0 + cl;
  float w[24];
  const float4v* xr = (const float4v*)(xs + cl * 100 + llb + 12);
#pragma unroll
  for (int j = 0; j < 6; ++j) {
    float4v t4 = xr[j];
    w[4 * j] = t4.x; w[4 * j + 1] = t4.y; w[4 * j + 2] = t4.z; w[4 * j + 3] = t4.w;
  }
  float wt[7];
#pragma unroll
  for (int tt = 0; tt < 7; ++tt) wt[tt] = dww[c * 7 + tt];
  float addv[16];
  if (t < 2) {
#pragma unroll
    for (int i = 0; i < 16; ++i) addv[i] = pcv[(size_t)(l0 + llb + i) * NC + c];
  } else {
    float bb = vb[c];
#pragma unroll
    for (int i = 0; i < 16; ++i) addv[i] = bb;
  }
#pragma unroll
  for (int i = 0; i < 16; ++i) {
    float acc = addv[i];
#pragma unroll
    for (int tt = 0; tt < 7; ++tt) acc += w[i + 1 + tt] * wt[tt];
    yT[((size_t)b * NL + l0 + llb + i) * NC + c] = f2b(acc);
  }
}

// ---- 128x128 MFMA GEMM core, BK=64, global-XOR-swizzled staging ------------
__device__ __forceinline__ void gemm_core_bk64(
    const unsigned short* __restrict__ A, const unsigned short* __restrict__ B,
    unsigned short* lA, unsigned short* lB, float4v acc[4][4], int m0, int n0) {
  int tid = threadIdx.x;
  int lane = tid & 63, quad = lane >> 4, l15 = lane & 15;
  int wave = tid >> 6, wr = wave >> 1, wc = wave & 1;
  const unsigned short* gA[4];
  const unsigned short* gB[4];
  unsigned short* dA[4];
  unsigned short* dB[4];
#pragma unroll
  for (int i = 0; i < 4; ++i) {
    int cc = tid + 256 * i;
    int row = cc >> 3;
    int gc = (cc & 7) ^ (row & 7);
    gA[i] = A + (size_t)(m0 + row) * 512 + gc * 8;
    gB[i] = B + (size_t)(n0 + row) * 512 + gc * 8;
    dA[i] = lA + cc * 8;
    dB[i] = lB + cc * 8;
  }
  for (int k0 = 0; k0 < 512; k0 += 64) {
#pragma unroll
    for (int i = 0; i < 4; ++i) gld16(gA[i] + k0, dA[i]);
#pragma unroll
    for (int i = 0; i < 4; ++i) gld16(gB[i] + k0, dB[i]);
    __syncthreads();
#pragma unroll
    for (int ks = 0; ks < 2; ++ks) {
      int sw = (ks * 4 + quad) ^ (l15 & 7);
      short8 af[4], bf[4];
#pragma unroll
      for (int mt = 0; mt < 4; ++mt)
        af[mt] = *(const short8*)(lA + (wr * 64 + mt * 16 + l15) * 64 + sw * 8);
#pragma unroll
      for (int nt = 0; nt < 4; ++nt)
        bf[nt] = *(const short8*)(lB + (wc * 64 + nt * 16 + l15) * 64 + sw * 8);
#pragma unroll
      for (int mt = 0; mt < 4; ++mt)
#pragma unroll
        for (int nt = 0; nt < 4; ++nt)
          acc[mt][nt] = bmfma(af[mt], bf[nt], acc[mt][nt]);
    }
    __syncthreads();
  }
}

// ---- fused pointwise GEMMs for q,k,v ---------------------------------------
// q output is pre-scaled by 0.125*log2(e) so attention can use exp2 directly.
__global__ __launch_bounds__(256) void pw_gemm_kernel(
    const unsigned short* __restrict__ wqm, const unsigned short* __restrict__ wkm,
    const unsigned short* __restrict__ wvm,
    const unsigned short* __restrict__ yq, const unsigned short* __restrict__ yk,
    const unsigned short* __restrict__ yv,
    const float* __restrict__ qb, const float* __restrict__ kb, const float* __restrict__ vb,
    unsigned short* __restrict__ qT, unsigned short* __restrict__ kT,
    unsigned short* __restrict__ vvo) {
  int z = blockIdx.z, t = z >> 5, b = z & 31;
  const unsigned short* W = (t == 0) ? wqm : (t == 1) ? wkm : wvm;
  const unsigned short* Y = ((t == 0) ? yq : (t == 1) ? yk : yv) + (size_t)b * NL * NC;
  const float* bias = (t == 0) ? qb : (t == 1) ? kb : vb;
  unsigned short* out = (t == 0) ? qT : (t == 1) ? kT : vvo;
  float oscale = (t == 0) ? 0.18033688011112042f : 1.0f;  // 0.125*log2(e) folded into q
  __shared__ __attribute__((aligned(16))) unsigned short buf[16384];
  unsigned short* lA = buf;
  unsigned short* lB = buf + 8192;
  int m0 = blockIdx.y * 128, n0 = blockIdx.x * 128;
  float4v acc[4][4];
#pragma unroll
  for (int i = 0; i < 4; ++i)
#pragma unroll
    for (int j = 0; j < 4; ++j) acc[i][j] = (float4v){0.f, 0.f, 0.f, 0.f};
  gemm_core_bk64(W, Y, lA, lB, acc, m0, n0);
  int tid = threadIdx.x;
  int lane = tid & 63, quad = lane >> 4, l15 = lane & 15;
  int wave = tid >> 6, wr = wave >> 1, wc = wave & 1;
  if (t < 2) {
#pragma unroll
    for (int mt = 0; mt < 4; ++mt) {
      int mloc = wr * 64 + mt * 16 + quad * 4;
#pragma unroll
      for (int nt = 0; nt < 4; ++nt) {
        int nloc = wc * 64 + nt * 16 + l15;
#pragma unroll
        for (int r = 0; r < 4; ++r) {
          int ml = mloc + r;
          buf[(ml >> 6) * 8192 + nloc * 64 + (ml & 63)] =
              f2b((acc[mt][nt][r] + bias[m0 + ml]) * oscale);
        }
      }
    }
    __syncthreads();
#pragma unroll
    for (int it = 0; it < 8; ++it) {
      int cc = tid + it * 256;
      int hloc = cc >> 10, l = (cc >> 3) & 127, dc = cc & 7;
      short8 vd = *(const short8*)(buf + hloc * 8192 + l * 64 + dc * 8);
      *(short8*)(out + (((size_t)b * NH + (m0 >> 6) + hloc) * NL + n0 + l) * NDK + dc * 8) = vd;
    }
  } else {
#pragma unroll
    for (int mt = 0; mt < 4; ++mt)
#pragma unroll
      for (int nt = 0; nt < 4; ++nt) {
        int n = n0 + wc * 64 + nt * 16 + l15;
#pragma unroll
        for (int r = 0; r < 4; ++r) {
          int m = m0 + wr * 64 + mt * 16 + quad * 4 + r;
          out[((size_t)b * NC + m) * NL + n] = f2b(acc[mt][nt][r] + bias[m]);
        }
      }
  }
}

// ---- persistent attention: one block per (b,h); K/V tiles dbuf in LDS ------
// Scores are tiny (|s|~1e-3) -> no max subtraction needed; q pre-scaled so
// p = exp2(s). Zero inner barriers: per-wave-private P transpose buffer.
__global__ __launch_bounds__(256, 1) void attn_kernel(
    const unsigned short* __restrict__ qT,  // (B,H,L,DK)
    const unsigned short* __restrict__ kT,  // (B,H,L,DK)
    const unsigned short* __restrict__ vv,  // (B,C,L)
    unsigned short* __restrict__ AO) {      // (B,C,L)
  int bh = blockIdx.x;
  int b = bh >> 3, h = bh & 7;
  int tid = threadIdx.x, wave = tid >> 6, lane = tid & 63, quad = lane >> 4, l15 = lane & 15;
  __shared__ __attribute__((aligned(16))) unsigned short Kt[2][128 * 64];  // [j][d] swizzled
  __shared__ __attribute__((aligned(16))) unsigned short Vt[2][64 * 128];  // [d][j] swizzled
  __shared__ __attribute__((aligned(16))) unsigned short Pt[4][16 * 136];  // per-wave, padded
  const unsigned short* qh = qT + (size_t)bh * NL * NDK;
  const unsigned short* kh = kT + (size_t)bh * NL * NDK;
  const unsigned short* vh = vv + ((size_t)b * NC + h * NDK) * NL;

  // staging chunk geometry (per thread, 4 K-chunks + 4 V-chunks per tile)
  int krow[4], kgc[4], vd[4], vgc[4];
#pragma unroll
  for (int ii = 0; ii < 4; ++ii) {
    int cc = tid + 256 * ii;
    krow[ii] = cc >> 3;
    kgc[ii] = (cc & 7) ^ (krow[ii] & 7);
    vd[ii] = cc >> 4;
    int c = cc & 15;
    vgc[ii] = (c & 8) | ((c & 7) ^ (vd[ii] & 7));
  }

  float4v o[8][4];
#pragma unroll
  for (int i = 0; i < 8; ++i)
#pragma unroll
    for (int j = 0; j < 4; ++j) o[i][j] = (float4v){0.f, 0.f, 0.f, 0.f};
  float lrun[8][4];
#pragma unroll
  for (int i = 0; i < 8; ++i)
#pragma unroll
    for (int r = 0; r < 4; ++r) lrun[i][r] = 0.f;

  // stage tile jt into buf
#define STAGE(jt_, buf_)                                                        \
  do {                                                                          \
    int j0_ = (jt_) * 128;                                                      \
    _Pragma("unroll") for (int ii = 0; ii < 4; ++ii)                            \
        gld16(kh + (size_t)(j0_ + krow[ii]) * NDK + kgc[ii] * 8,                \
              &Kt[buf_][(tid + 256 * ii) * 8]);                                 \
    _Pragma("unroll") for (int ii = 0; ii < 4; ++ii)                            \
        gld16(vh + (size_t)vd[ii] * NL + j0_ + vgc[ii] * 8,                     \
              &Vt[buf_][(tid + 256 * ii) * 8]);                                 \
  } while (0)

  STAGE(0, 0);

  const unsigned short* qbase = qh + (size_t)(wave * 128 + l15) * NDK + quad * 8;
  short8 nq0 = *(const short8*)(qbase);
  short8 nq1 = *(const short8*)(qbase + 32);
  unsigned short* P = &Pt[wave][0];

  for (int jt = 0; jt < 4; ++jt) {
    __syncthreads();  // drains prev prefetch vmcnt; tiles for jt now visible
    if (jt < 3) STAGE(jt + 1, (jt + 1) & 1);
    const unsigned short* K = &Kt[jt & 1][0];
    const unsigned short* V = &Vt[jt & 1][0];
    // hoist K and V fragments for this tile
    short8 kb[8][2], av[4][4];
#pragma unroll
    for (int n4 = 0; n4 < 8; ++n4)
#pragma unroll
      for (int hf = 0; hf < 2; ++hf)
        kb[n4][hf] = *(const short8*)(K + (n4 * 16 + l15) * 64 +
                                      (((hf * 4 + quad) ^ (l15 & 7)) << 3));
#pragma unroll
    for (int mt = 0; mt < 4; ++mt)
#pragma unroll
      for (int ks = 0; ks < 4; ++ks) {
        int c = ks * 4 + quad;
        av[mt][ks] = *(const short8*)(V + (mt * 16 + l15) * 128 +
                                      (((c & 8) | ((c & 7) ^ (l15 & 7))) << 3));
      }
#pragma unroll
    for (int iset = 0; iset < 8; ++iset) {
      short8 a0 = nq0, a1 = nq1;
      // rolling Q prefetch (from global; Q region is L2-resident after jt 0)
      int nxt = (iset < 7) ? (iset + 1) : 0;
      if (!(jt == 3 && iset == 7)) {
        nq0 = *(const short8*)(qbase + (size_t)nxt * 1024);
        nq1 = *(const short8*)(qbase + (size_t)nxt * 1024 + 32);
      }
      float4v s[8];
#pragma unroll
      for (int n4 = 0; n4 < 8; ++n4) {
        float4v acc = {0.f, 0.f, 0.f, 0.f};
        acc = bmfma(a0, kb[n4][0], acc);
        acc = bmfma(a1, kb[n4][1], acc);
        s[n4] = acc;
      }
#pragma unroll
      for (int n4 = 0; n4 < 8; ++n4)
#pragma unroll
        for (int r = 0; r < 4; ++r) {
          float p = __builtin_amdgcn_exp2f(s[n4][r]);
          s[n4][r] = p;
          lrun[iset][r] += p;
        }
#pragma unroll
      for (int n4 = 0; n4 < 8; ++n4)
#pragma unroll
        for (int r = 0; r < 4; ++r)
          P[(quad * 4 + r) * 136 + n4 * 16 + l15] = f2b(s[n4][r]);
      // PV for this iset (same wave: lgkm ordering only, no barrier)
#pragma unroll
      for (int ks = 0; ks < 4; ++ks) {
        short8 pb = *(const short8*)(P + l15 * 136 + ks * 32 + quad * 8);
#pragma unroll
        for (int mt = 0; mt < 4; ++mt)
          o[iset][mt] = bmfma(av[mt][ks], pb, o[iset][mt]);
      }
    }
  }

  // finalize row sums: in-lane partials -> cross-l15 reduce
#pragma unroll
  for (int iset = 0; iset < 8; ++iset)
#pragma unroll
    for (int r = 0; r < 4; ++r) {
      float v = lrun[iset][r];
      v += __shfl_xor(v, 1);
      v += __shfl_xor(v, 2);
      v += __shfl_xor(v, 4);
      v += __shfl_xor(v, 8);
      lrun[iset][r] = v;
    }
  // redistribute 1/l from (quad,r) indexing to l15 indexing via LDS (Kt free)
  float* lsh = (float*)&Kt[0][0];
  if (l15 == 0) {
#pragma unroll
    for (int iset = 0; iset < 8; ++iset)
#pragma unroll
      for (int r = 0; r < 4; ++r)
        lsh[wave * 128 + iset * 16 + quad * 4 + r] = lrun[iset][r];
  }
  // same-wave LDS dependency: compiler inserts lgkm wait
#pragma unroll
  for (int iset = 0; iset < 8; ++iset) {
    float li = __builtin_amdgcn_rcpf(lsh[wave * 128 + iset * 16 + l15]);
    int lpos = wave * 128 + iset * 16 + l15;
#pragma unroll
    for (int mt = 0; mt < 4; ++mt)
#pragma unroll
      for (int r = 0; r < 4; ++r) {
        int d = mt * 16 + quad * 4 + r;
        AO[((size_t)b * NC + h * NDK + d) * NL + lpos] = f2b(o[iset][mt][r] * li);
      }
  }
#undef STAGE
}

// ---- final projection GEMM (fp32 out) --------------------------------------
__global__ __launch_bounds__(256) void final_gemm_kernel(
    const unsigned short* __restrict__ AO, const unsigned short* __restrict__ W,
    const float* __restrict__ bias, float* __restrict__ out) {
  int b = blockIdx.z;
  __shared__ __attribute__((aligned(16))) unsigned short buf[16384];
  unsigned short* lA = buf;
  unsigned short* lB = buf + 8192;
  int m0 = blockIdx.y * 128, n0 = blockIdx.x * 128;
  float4v acc[4][4];
#pragma unroll
  for (int i = 0; i < 4; ++i)
#pragma unroll
    for (int j = 0; j < 4; ++j) acc[i][j] = (float4v){0.f, 0.f, 0.f, 0.f};
  gemm_core_bk64(AO + (size_t)b * 512 * 512, W, lA, lB, acc, m0, n0);
  int lane = threadIdx.x & 63, quad = lane >> 4, l15 = lane & 15;
  int wave = threadIdx.x >> 6, wr = wave >> 1, wc = wave & 1;
#pragma unroll
  for (int mt = 0; mt < 4; ++mt)
#pragma unroll
    for (int nt = 0; nt < 4; ++nt) {
      int n = n0 + wc * 64 + nt * 16 + l15;
      float bn = bias[n];
#pragma unroll
      for (int r = 0; r < 4; ++r) {
        int m = m0 + wr * 64 + mt * 16 + quad * 4 + r;
        out[((size_t)b * 512 + m) * 512 + n] = acc[mt][nt][r] + bn;
      }
    }
}

extern "C" void kernel_launch(void* const* d_in, const int* in_sizes, int n_in,
                              void* d_out, int out_size, void* d_ws, size_t ws_size,
                              hipStream_t stream) {
  (void)in_sizes; (void)n_in; (void)out_size; (void)ws_size;
  const float* query  = (const float*)d_in[0];
  const float* key    = (const float*)d_in[1];
  const float* value  = (const float*)d_in[2];
  const float* pos    = (const float*)d_in[3];
  const float* proj_w = (const float*)d_in[4];
  const float* proj_b = (const float*)d_in[5];
  const float* q_dw_w = (const float*)d_in[6];
  const float* q_dw_b = (const float*)d_in[7];
  const float* q_pw_w = (const float*)d_in[8];
  const float* q_pw_b = (const float*)d_in[9];
  const float* k_dw_w = (const float*)d_in[10];
  const float* k_dw_b = (const float*)d_in[11];
  const float* k_pw_w = (const float*)d_in[12];
  const float* k_pw_b = (const float*)d_in[13];
  const float* v_dw_w = (const float*)d_in[14];
  const float* v_dw_b = (const float*)d_in[15];
  const float* v_pw_w = (const float*)d_in[16];
  const float* v_pw_b = (const float*)d_in[17];

  char* ws = (char*)d_ws;
  const size_t WMAT = (size_t)512 * 512 * 2;     // 512 KB
  const size_t TEN  = (size_t)NB * NC * NL * 2;  // 16 MB
  unsigned short* wq  = (unsigned short*)(ws);
  unsigned short* wk  = (unsigned short*)(ws + WMAT);
  unsigned short* wv  = (unsigned short*)(ws + 2 * WMAT);
  unsigned short* wp  = (unsigned short*)(ws + 3 * WMAT);
  unsigned short* yq  = (unsigned short*)(ws + 4 * WMAT);
  unsigned short* yk  = (unsigned short*)(ws + 4 * WMAT + TEN);
  unsigned short* yv  = (unsigned short*)(ws + 4 * WMAT + 2 * TEN);
  unsigned short* qT  = (unsigned short*)(ws + 4 * WMAT + 3 * TEN);
  unsigned short* kT  = (unsigned short*)(ws + 4 * WMAT + 4 * TEN);
  unsigned short* vvb = (unsigned short*)(ws + 4 * WMAT + 5 * TEN);
  unsigned short* AO  = yq;  // yq fully consumed by pw(q) before attention writes
  float* pqc = (float*)qT;   // posconv buffers consumed by dw before pw writes qT
  float* pkc = (float*)(ws + 4 * WMAT + 3 * TEN + (size_t)NL * NC * 4);

  cvt4_kernel<<<dim3(256, 4), 256, 0, stream>>>(q_pw_w, k_pw_w, v_pw_w, proj_w, wq, wk, wv, wp);

  posconv_kernel<<<dim3(512, 2), 256, 0, stream>>>(pos, q_dw_w, q_dw_b, k_dw_w, k_dw_b, pqc, pkc);

  dw_kernel<<<dim3(8, 8, 96), 256, 0, stream>>>(
      query, key, value, pqc, pkc, q_dw_w, k_dw_w, v_dw_w, v_dw_b, yq, yk, yv);

  pw_gemm_kernel<<<dim3(4, 4, 96), 256, 0, stream>>>(
      wq, wk, wv, yq, yk, yv, q_pw_b, k_pw_b, v_pw_b, qT, kT, vvb);

  attn_kernel<<<dim3(256), 256, 0, stream>>>(qT, kT, vvb, AO);

  final_gemm_kernel<<<dim3(4, 4, 32), 256, 0, stream>>>(AO, wp, proj_b, (float*)d_out);
}

// Round 5
// 290.803 us; speedup vs baseline: 1.1952x; 1.1952x over previous
//
#include <hip/hip_runtime.h>

typedef __attribute__((ext_vector_type(8))) short short8;
typedef __attribute__((ext_vector_type(4))) float float4v;
typedef __attribute__((ext_vector_type(16))) float float16v;
typedef __attribute__((ext_vector_type(4))) unsigned short ushort4v;

#define NB 32
#define NC 512
#define NL 512
#define NH 8
#define NDK 64

__device__ __forceinline__ unsigned short f2b(float f) {
  union { float f; unsigned int u; } v; v.f = f;
  unsigned int r = v.u + 0x7FFFu + ((v.u >> 16) & 1u);
  return (unsigned short)(r >> 16);
}

__device__ __forceinline__ void gld16(const void* g, void* l) {
  __builtin_amdgcn_global_load_lds(
      (const __attribute__((address_space(1))) unsigned int*)g,
      (__attribute__((address_space(3))) unsigned int*)l, 16, 0, 0);
}

__device__ __forceinline__ float4v bmfma(short8 a, short8 b, float4v c) {
  return __builtin_amdgcn_mfma_f32_16x16x32_bf16(a, b, c, 0, 0, 0);
}

// ---- fp32 -> bf16 weight conversion, 4 matrices in one launch --------------
__global__ __launch_bounds__(256) void cvt4_kernel(
    const float* __restrict__ a, const float* __restrict__ b,
    const float* __restrict__ c, const float* __restrict__ d,
    unsigned short* __restrict__ oa, unsigned short* __restrict__ ob,
    unsigned short* __restrict__ oc, unsigned short* __restrict__ od) {
  int m = blockIdx.y;
  const float* src = (m == 0) ? a : (m == 1) ? b : (m == 2) ? c : d;
  unsigned short* dst = (m == 0) ? oa : (m == 1) ? ob : (m == 2) ? oc : od;
  int i = (blockIdx.x * 256 + threadIdx.x) * 4;
  float4v v = *(const float4v*)(src + i);
  ushort4v o;
  o.x = f2b(v.x); o.y = f2b(v.y); o.z = f2b(v.z); o.w = f2b(v.w);
  *(ushort4v*)(dst + i) = o;
}

// ---- posconv: conv(pos, dw_w) + dw_b, batch-independent; out (L,C) fp32 ----
__global__ __launch_bounds__(256) void posconv_kernel(
    const float* __restrict__ pos,
    const float* __restrict__ qw, const float* __restrict__ qb,
    const float* __restrict__ kw, const float* __restrict__ kb,
    float* __restrict__ pq, float* __restrict__ pk) {
  int t = blockIdx.y, l = blockIdx.x;
  const float* w  = t ? kw : qw;
  const float* bb = t ? kb : qb;
  float* outp = t ? pk : pq;
  for (int c = threadIdx.x; c < NC; c += 256) {
    float acc = bb[c];
#pragma unroll
    for (int tt = 0; tt < 7; ++tt) {
      int ll = l + tt - 3;
      if (ll >= 0 && ll < NL) acc += pos[(size_t)ll * NC + c] * w[c * 7 + tt];
    }
    outp[(size_t)l * NC + c] = acc;
  }
}

// ---- depthwise conv(7); posconv(+bias) added for q,k; writes yT (B,L,C) ----
__global__ __launch_bounds__(256) void dw_kernel(
    const float* __restrict__ q, const float* __restrict__ k, const float* __restrict__ v,
    const float* __restrict__ pq, const float* __restrict__ pk,
    const float* __restrict__ qw, const float* __restrict__ kw, const float* __restrict__ vw,
    const float* __restrict__ vb,
    unsigned short* __restrict__ yq, unsigned short* __restrict__ yk,
    unsigned short* __restrict__ yv) {
  int z = blockIdx.z;
  int t = z >> 5, b = z & 31;
  const float* x   = (t == 0) ? q  : (t == 1) ? k  : v;
  const float* dww = (t == 0) ? qw : (t == 1) ? kw : vw;
  const float* pcv = (t == 0) ? pq : pk;  // only used when t<2
  unsigned short* yT = (t == 0) ? yq : (t == 1) ? yk : yv;
  int c0 = blockIdx.y * 64, l0 = blockIdx.x * 64;
  int tid = threadIdx.x;
  __shared__ __attribute__((aligned(16))) float xs[64 * 100];
#pragma unroll
  for (int it = 0; it < 6; ++it) {
    int idx = tid + 256 * it;  // 0..1535
    int row = idx / 24, f4 = idx - row * 24;
    int l = l0 - 16 + f4 * 4;
    const float* px = x + ((size_t)b * NC + c0 + row) * NL + l;
    float v0 = 0.f, v1 = 0.f, v2 = 0.f, v3 = 0.f;
    if (l >= 0 && l + 3 < NL) {
      float4v vv = *(const float4v*)px;
      v0 = vv.x; v1 = vv.y; v2 = vv.z; v3 = vv.w;
    } else {
      if (l + 0 >= 0 && l + 0 < NL) v0 = px[0];
      if (l + 1 >= 0 && l + 1 < NL) v1 = px[1];
      if (l + 2 >= 0 && l + 2 < NL) v2 = px[2];
      if (l + 3 >= 0 && l + 3 < NL) v3 = px[3];
    }
    float* xr = xs + row * 100 + f4 * 4;
    xr[0] = v0; xr[1] = v1; xr[2] = v2; xr[3] = v3;
  }
  __syncthreads();
  int cl = tid & 63;
  int llb = (tid >> 6) * 16;
  int c = c0 + cl;
  float w[24];
  const float4v* xr = (const float4v*)(xs + cl * 100 + llb + 12);
#pragma unroll
  for (int j = 0; j < 6; ++j) {
    float4v t4 = xr[j];
    w[4 * j] = t4.x; w[4 * j + 1] = t4.y; w[4 * j + 2] = t4.z; w[4 * j + 3] = t4.w;
  }
  float wt[7];
#pragma unroll
  for (int tt = 0; tt < 7; ++tt) wt[tt] = dww[c * 7 + tt];
  float addv[16];
  if (t < 2) {
#pragma unroll
    for (int i = 0; i < 16; ++i) addv[i] = pcv[(size_t)(l0 + llb + i) * NC + c];
  } else {
    float bb = vb[c];
#pragma unroll
    for (int i = 0; i < 16; ++i) addv[i] = bb;
  }
#pragma unroll
  for (int i = 0; i < 16; ++i) {
    float acc = addv[i];
#pragma unroll
    for (int tt = 0; tt < 7; ++tt) acc += w[i + 1 + tt] * wt[tt];
    yT[((size_t)b * NL + l0 + llb + i) * NC + c] = f2b(acc);
  }
}

// ---- 128x128 MFMA GEMM core, BK=64, global-XOR-swizzled staging ------------
__device__ __forceinline__ void gemm_core_bk64(
    const unsigned short* __restrict__ A, const unsigned short* __restrict__ B,
    unsigned short* lA, unsigned short* lB, float4v acc[4][4], int m0, int n0) {
  int tid = threadIdx.x;
  int lane = tid & 63, quad = lane >> 4, l15 = lane & 15;
  int wave = tid >> 6, wr = wave >> 1, wc = wave & 1;
  const unsigned short* gA[4];
  const unsigned short* gB[4];
  unsigned short* dA[4];
  unsigned short* dB[4];
#pragma unroll
  for (int i = 0; i < 4; ++i) {
    int cc = tid + 256 * i;
    int row = cc >> 3;
    int gc = (cc & 7) ^ (row & 7);
    gA[i] = A + (size_t)(m0 + row) * 512 + gc * 8;
    gB[i] = B + (size_t)(n0 + row) * 512 + gc * 8;
    dA[i] = lA + cc * 8;
    dB[i] = lB + cc * 8;
  }
  for (int k0 = 0; k0 < 512; k0 += 64) {
#pragma unroll
    for (int i = 0; i < 4; ++i) gld16(gA[i] + k0, dA[i]);
#pragma unroll
    for (int i = 0; i < 4; ++i) gld16(gB[i] + k0, dB[i]);
    __syncthreads();
#pragma unroll
    for (int ks = 0; ks < 2; ++ks) {
      int sw = (ks * 4 + quad) ^ (l15 & 7);
      short8 af[4], bf[4];
#pragma unroll
      for (int mt = 0; mt < 4; ++mt)
        af[mt] = *(const short8*)(lA + (wr * 64 + mt * 16 + l15) * 64 + sw * 8);
#pragma unroll
      for (int nt = 0; nt < 4; ++nt)
        bf[nt] = *(const short8*)(lB + (wc * 64 + nt * 16 + l15) * 64 + sw * 8);
#pragma unroll
      for (int mt = 0; mt < 4; ++mt)
#pragma unroll
        for (int nt = 0; nt < 4; ++nt)
          acc[mt][nt] = bmfma(af[mt], bf[nt], acc[mt][nt]);
    }
    __syncthreads();
  }
}

// ---- fused pointwise GEMMs for q,k,v ---------------------------------------
// q output is pre-scaled by 0.125*log2(e) so attention can use exp2 directly.
__global__ __launch_bounds__(256) void pw_gemm_kernel(
    const unsigned short* __restrict__ wqm, const unsigned short* __restrict__ wkm,
    const unsigned short* __restrict__ wvm,
    const unsigned short* __restrict__ yq, const unsigned short* __restrict__ yk,
    const unsigned short* __restrict__ yv,
    const float* __restrict__ qb, const float* __restrict__ kb, const float* __restrict__ vb,
    unsigned short* __restrict__ qT, unsigned short* __restrict__ kT,
    unsigned short* __restrict__ vvo) {
  int z = blockIdx.z, t = z >> 5, b = z & 31;
  const unsigned short* W = (t == 0) ? wqm : (t == 1) ? wkm : wvm;
  const unsigned short* Y = ((t == 0) ? yq : (t == 1) ? yk : yv) + (size_t)b * NL * NC;
  const float* bias = (t == 0) ? qb : (t == 1) ? kb : vb;
  unsigned short* out = (t == 0) ? qT : (t == 1) ? kT : vvo;
  float oscale = (t == 0) ? 0.18033688011112042f : 1.0f;  // 0.125*log2(e) folded into q
  __shared__ __attribute__((aligned(16))) unsigned short buf[16384];
  unsigned short* lA = buf;
  unsigned short* lB = buf + 8192;
  int m0 = blockIdx.y * 128, n0 = blockIdx.x * 128;
  float4v acc[4][4];
#pragma unroll
  for (int i = 0; i < 4; ++i)
#pragma unroll
    for (int j = 0; j < 4; ++j) acc[i][j] = (float4v){0.f, 0.f, 0.f, 0.f};
  gemm_core_bk64(W, Y, lA, lB, acc, m0, n0);
  int tid = threadIdx.x;
  int lane = tid & 63, quad = lane >> 4, l15 = lane & 15;
  int wave = tid >> 6, wr = wave >> 1, wc = wave & 1;
  if (t < 2) {
#pragma unroll
    for (int mt = 0; mt < 4; ++mt) {
      int mloc = wr * 64 + mt * 16 + quad * 4;
#pragma unroll
      for (int nt = 0; nt < 4; ++nt) {
        int nloc = wc * 64 + nt * 16 + l15;
#pragma unroll
        for (int r = 0; r < 4; ++r) {
          int ml = mloc + r;
          buf[(ml >> 6) * 8192 + nloc * 64 + (ml & 63)] =
              f2b((acc[mt][nt][r] + bias[m0 + ml]) * oscale);
        }
      }
    }
    __syncthreads();
#pragma unroll
    for (int it = 0; it < 8; ++it) {
      int cc = tid + it * 256;
      int hloc = cc >> 10, l = (cc >> 3) & 127, dc = cc & 7;
      short8 vd = *(const short8*)(buf + hloc * 8192 + l * 64 + dc * 8);
      *(short8*)(out + (((size_t)b * NH + (m0 >> 6) + hloc) * NL + n0 + l) * NDK + dc * 8) = vd;
    }
  } else {
#pragma unroll
    for (int mt = 0; mt < 4; ++mt)
#pragma unroll
      for (int nt = 0; nt < 4; ++nt) {
        int n = n0 + wc * 64 + nt * 16 + l15;
#pragma unroll
        for (int r = 0; r < 4; ++r) {
          int m = m0 + wr * 64 + mt * 16 + quad * 4 + r;
          out[((size_t)b * NC + m) * NL + n] = f2b(acc[mt][nt][r] + bias[m]);
        }
      }
  }
}

// ---- persistent attention, i-outer / j-inner: full K,V resident in LDS -----
// One block per (b,h). K (512x64) + V (64x512) staged ONCE (128 KB LDS).
// Each wave owns 128 i-rows = 4 isets of 32, processed with 32x32x16 MFMA.
// Only per-iset state lives in registers (~130 VGPR) -> no spill.
// exp2-only softmax (q pre-scaled, scores tiny -> no max subtraction).
__global__ __launch_bounds__(256, 1) void attn_kernel(
    const unsigned short* __restrict__ qT,  // (B,H,L,DK)
    const unsigned short* __restrict__ kT,  // (B,H,L,DK)
    const unsigned short* __restrict__ vv,  // (B,C,L)
    unsigned short* __restrict__ AO) {      // (B,C,L)
  int bh = blockIdx.x, b = bh >> 3, h = bh & 7;
  int tid = threadIdx.x, wave = tid >> 6, lane = tid & 63;
  int l31 = lane & 31, lh = lane >> 5;
  __shared__ __attribute__((aligned(16))) unsigned short Kt[512 * 64];  // [j][d] swz
  __shared__ __attribute__((aligned(16))) unsigned short Vt[64 * 512];  // [d][j] swz
  __shared__ __attribute__((aligned(16))) unsigned short Pt[4][32 * 64];  // per-wave
  __shared__ float lsh[4][32];
  const unsigned short* qh = qT + (size_t)bh * NL * NDK;
  const unsigned short* kh = kT + (size_t)bh * NL * NDK;
  const unsigned short* vh = vv + ((size_t)b * NC + h * NDK) * NL;

  // one-time stage of all K and V (swizzle realized on the global side)
#pragma unroll
  for (int ii = 0; ii < 16; ++ii) {
    int cc = tid + 256 * ii;
    int row = cc >> 3, c = (cc & 7) ^ (row & 7);
    gld16(kh + (size_t)row * NDK + c * 8, &Kt[cc * 8]);
  }
#pragma unroll
  for (int ii = 0; ii < 16; ++ii) {
    int cc = tid + 256 * ii;
    int d = cc >> 6, pc = cc & 63;
    int c = (pc & ~7) | ((pc & 7) ^ (d & 7));
    gld16(vh + (size_t)d * NL + c * 8, &Vt[cc * 8]);
  }
  __syncthreads();  // only barrier in the kernel

  unsigned short* P = &Pt[wave][0];
  int irow = (0 & 3);  (void)irow;
  for (int iset = 0; iset < 4; ++iset) {
    int i0 = wave * 128 + iset * 32;
    // Q fragments: A[m=i][k=d], m=lane&31, k=(lane>>5)*8 + s*16
    short8 a[4];
#pragma unroll
    for (int s = 0; s < 4; ++s)
      a[s] = *(const short8*)(qh + (size_t)(i0 + l31) * NDK + s * 16 + lh * 8);
    float16v o0, o1;
#pragma unroll
    for (int r = 0; r < 16; ++r) { o0[r] = 0.f; o1[r] = 0.f; }
    float lrun[16];
#pragma unroll
    for (int r = 0; r < 16; ++r) lrun[r] = 0.f;

    for (int jt = 0; jt < 8; ++jt) {
      int j0 = jt * 64;
      // S = Q K^T : 2 n-tiles of 32 j
#pragma unroll
      for (int nt = 0; nt < 2; ++nt) {
        int j = j0 + nt * 32 + l31;
        float16v sacc;
#pragma unroll
        for (int r = 0; r < 16; ++r) sacc[r] = 0.f;
#pragma unroll
        for (int s = 0; s < 4; ++s) {
          int c = (s * 2 + lh) ^ (j & 7);
          short8 kbf = *(const short8*)(&Kt[(size_t)j * 64 + c * 8]);
          sacc = __builtin_amdgcn_mfma_f32_32x32x16_bf16(a[s], kbf, sacc, 0, 0, 0);
        }
        // p = exp2(s); accumulate row sums; write P (row i, col j, swz)
#pragma unroll
        for (int r = 0; r < 16; ++r) {
          float p = __builtin_amdgcn_exp2f(sacc[r]);
          lrun[r] += p;
          int iL = (r & 3) + 8 * (r >> 2) + 4 * lh;
          int col = nt * 32 + l31;
          P[iL * 64 + ((((col >> 3) ^ (iL & 7)) << 3) | (col & 7))] = f2b(p);
        }
      }
      // O += V P^T : A[m=d][k=j] from Vt, B[n=i][k=j] from P
#pragma unroll
      for (int s = 0; s < 4; ++s) {
        int pc = (s * 2 + lh) ^ (l31 & 7);
        short8 pb = *(const short8*)(&P[l31 * 64 + pc * 8]);
        {
          int d = l31;  // dt = 0
          int c = (j0 >> 3) + s * 2 + lh;
          int vc = (c & ~7) | ((c & 7) ^ (d & 7));
          short8 av = *(const short8*)(&Vt[(size_t)d * 512 + vc * 8]);
          o0 = __builtin_amdgcn_mfma_f32_32x32x16_bf16(av, pb, o0, 0, 0, 0);
        }
        {
          int d = 32 + l31;  // dt = 1
          int c = (j0 >> 3) + s * 2 + lh;
          int vc = (c & ~7) | ((c & 7) ^ (d & 7));
          short8 av = *(const short8*)(&Vt[(size_t)d * 512 + vc * 8]);
          o1 = __builtin_amdgcn_mfma_f32_32x32x16_bf16(av, pb, o1, 0, 0, 0);
        }
      }
    }
    // row sums: reduce across the 32 j-lanes of each half
#pragma unroll
    for (int r = 0; r < 16; ++r) {
      float v = lrun[r];
      v += __shfl_xor(v, 1);
      v += __shfl_xor(v, 2);
      v += __shfl_xor(v, 4);
      v += __shfl_xor(v, 8);
      v += __shfl_xor(v, 16);
      lrun[r] = v;
    }
    if (l31 == 0) {
#pragma unroll
      for (int r = 0; r < 16; ++r)
        lsh[wave][(r & 3) + 8 * (r >> 2) + 4 * lh] = lrun[r];
    }
    // same-wave LDS dep: compiler inserts lgkm wait
    float li = __builtin_amdgcn_rcpf(lsh[wave][l31]);
#pragma unroll
    for (int r = 0; r < 16; ++r) {
      int dr = (r & 3) + 8 * (r >> 2) + 4 * lh;
      AO[((size_t)b * NC + h * NDK + dr) * NL + i0 + l31] = f2b(o0[r] * li);
      AO[((size_t)b * NC + h * NDK + 32 + dr) * NL + i0 + l31] = f2b(o1[r] * li);
    }
  }
}

// ---- final projection GEMM (fp32 out) --------------------------------------
__global__ __launch_bounds__(256) void final_gemm_kernel(
    const unsigned short* __restrict__ AO, const unsigned short* __restrict__ W,
    const float* __restrict__ bias, float* __restrict__ out) {
  int b = blockIdx.z;
  __shared__ __attribute__((aligned(16))) unsigned short buf[16384];
  unsigned short* lA = buf;
  unsigned short* lB = buf + 8192;
  int m0 = blockIdx.y * 128, n0 = blockIdx.x * 128;
  float4v acc[4][4];
#pragma unroll
  for (int i = 0; i < 4; ++i)
#pragma unroll
    for (int j = 0; j < 4; ++j) acc[i][j] = (float4v){0.f, 0.f, 0.f, 0.f};
  gemm_core_bk64(AO + (size_t)b * 512 * 512, W, lA, lB, acc, m0, n0);
  int lane = threadIdx.x & 63, quad = lane >> 4, l15 = lane & 15;
  int wave = threadIdx.x >> 6, wr = wave >> 1, wc = wave & 1;
#pragma unroll
  for (int mt = 0; mt < 4; ++mt)
#pragma unroll
    for (int nt = 0; nt < 4; ++nt) {
      int n = n0 + wc * 64 + nt * 16 + l15;
      float bn = bias[n];
#pragma unroll
      for (int r = 0; r < 4; ++r) {
        int m = m0 + wr * 64 + mt * 16 + quad * 4 + r;
        out[((size_t)b * 512 + m) * 512 + n] = acc[mt][nt][r] + bn;
      }
    }
}

extern "C" void kernel_launch(void* const* d_in, const int* in_sizes, int n_in,
                              void* d_out, int out_size, void* d_ws, size_t ws_size,
                              hipStream_t stream) {
  (void)in_sizes; (void)n_in; (void)out_size; (void)ws_size;
  const float* query  = (const float*)d_in[0];
  const float* key    = (const float*)d_in[1];
  const float* value  = (const float*)d_in[2];
  const float* pos    = (const float*)d_in[3];
  const float* proj_w = (const float*)d_in[4];
  const float* proj_b = (const float*)d_in[5];
  const float* q_dw_w = (const float*)d_in[6];
  const float* q_dw_b = (const float*)d_in[7];
  const float* q_pw_w = (const float*)d_in[8];
  const float* q_pw_b = (const float*)d_in[9];
  const float* k_dw_w = (const float*)d_in[10];
  const float* k_dw_b = (const float*)d_in[11];
  const float* k_pw_w = (const float*)d_in[12];
  const float* k_pw_b = (const float*)d_in[13];
  const float* v_dw_w = (const float*)d_in[14];
  const float* v_dw_b = (const float*)d_in[15];
  const float* v_pw_w = (const float*)d_in[16];
  const float* v_pw_b = (const float*)d_in[17];

  char* ws = (char*)d_ws;
  const size_t WMAT = (size_t)512 * 512 * 2;     // 512 KB
  const size_t TEN  = (size_t)NB * NC * NL * 2;  // 16 MB
  unsigned short* wq  = (unsigned short*)(ws);
  unsigned short* wk  = (unsigned short*)(ws + WMAT);
  unsigned short* wv  = (unsigned short*)(ws + 2 * WMAT);
  unsigned short* wp  = (unsigned short*)(ws + 3 * WMAT);
  unsigned short* yq  = (unsigned short*)(ws + 4 * WMAT);
  unsigned short* yk  = (unsigned short*)(ws + 4 * WMAT + TEN);
  unsigned short* yv  = (unsigned short*)(ws + 4 * WMAT + 2 * TEN);
  unsigned short* qT  = (unsigned short*)(ws + 4 * WMAT + 3 * TEN);
  unsigned short* kT  = (unsigned short*)(ws + 4 * WMAT + 4 * TEN);
  unsigned short* vvb = (unsigned short*)(ws + 4 * WMAT + 5 * TEN);
  unsigned short* AO  = yq;  // yq fully consumed by pw(q) before attention writes
  float* pqc = (float*)qT;   // posconv buffers consumed by dw before pw writes qT
  float* pkc = (float*)(ws + 4 * WMAT + 3 * TEN + (size_t)NL * NC * 4);

  cvt4_kernel<<<dim3(256, 4), 256, 0, stream>>>(q_pw_w, k_pw_w, v_pw_w, proj_w, wq, wk, wv, wp);

  posconv_kernel<<<dim3(512, 2), 256, 0, stream>>>(pos, q_dw_w, q_dw_b, k_dw_w, k_dw_b, pqc, pkc);

  dw_kernel<<<dim3(8, 8, 96), 256, 0, stream>>>(
      query, key, value, pqc, pkc, q_dw_w, k_dw_w, v_dw_w, v_dw_b, yq, yk, yv);

  pw_gemm_kernel<<<dim3(4, 4, 96), 256, 0, stream>>>(
      wq, wk, wv, yq, yk, yv, q_pw_b, k_pw_b, v_pw_b, qT, kT, vvb);

  attn_kernel<<<dim3(256), 256, 0, stream>>>(qT, kT, vvb, AO);

  final_gemm_kernel<<<dim3(4, 4, 32), 256, 0, stream>>>(AO, wp, proj_b, (float*)d_out);
}